// Round 1
// baseline (682.552 us; speedup 1.0000x reference)
//
#include <hip/hip_runtime.h>

typedef unsigned int u32;
typedef unsigned short u16;
typedef __bf16 bf16x8 __attribute__((ext_vector_type(8)));
typedef float f32x16 __attribute__((ext_vector_type(16)));

// ---------- helpers ----------
__device__ __forceinline__ u16 f2bf(float f) {
  u32 u = __float_as_uint(f);
  u32 r = (u + 0x7FFFu + ((u >> 16) & 1u)) >> 16;
  return (u16)r;
}

__device__ __forceinline__ float fast_tanh(float x) {
  // tanh(x) = 1 - 2/(exp(2x)+1); robust at +-inf
  float e = __expf(2.0f * x);
  return 1.0f - 2.0f * __builtin_amdgcn_rcpf(e + 1.0f);
}

__device__ __forceinline__ void glds16(const void* g, void* l) {
  __builtin_amdgcn_global_load_lds(
      (__attribute__((address_space(1))) void*)g,
      (__attribute__((address_space(3))) void*)l, 16, 0, 0);
}

// bilinear interp matching jnp.searchsorted(side='right')-1 with clamping
__device__ __forceinline__ float inter2d_d(const float* xs, const float* ys,
                                           const float* tb, float xq, float yq) {
  xq = fminf(fmaxf(xq, xs[0]), xs[8]);
  yq = fminf(fmaxf(yq, ys[0]), ys[13]);
  int i = 0, j = 0;
#pragma unroll
  for (int k = 1; k <= 8; ++k) if (xq >= xs[k]) i = k;
#pragma unroll
  for (int k = 1; k <= 13; ++k) if (yq >= ys[k]) j = k;
  if (i > 7) i = 7;
  if (j > 12) j = 12;
  float x0 = xs[i], x1 = xs[i + 1], y0 = ys[j], y1 = ys[j + 1];
  float tx = (xq - x0) / (x1 - x0);
  float ty = (yq - y0) / (y1 - y0);
  float f00 = tb[i * 14 + j], f01 = tb[i * 14 + j + 1];
  float f10 = tb[(i + 1) * 14 + j], f11 = tb[(i + 1) * 14 + j + 1];
  return f00 * (1 - tx) * (1 - ty) + f10 * tx * (1 - ty) +
         f01 * (1 - tx) * ty + f11 * tx * ty;
}

// ---------- kernel 1: moments of u (4 means + 10 second moments) ----------
__global__ void stats1_kernel(const float* __restrict__ x,
                              const float* __restrict__ tsg,
                              const float* __restrict__ teg,
                              const float* __restrict__ tbg,
                              float* __restrict__ mom) {
  __shared__ float ts[9], te[14], tb[126], bacc[14];
  int t = threadIdx.x;
  if (t < 9) ts[t] = tsg[t];
  if (t < 14) { te[t] = teg[t]; bacc[t] = 0.f; }
  if (t < 126) tb[t] = tbg[t];
  __syncthreads();
  const float* xr = x + (size_t)(blockIdx.x * 256 + t) * 15;
  float amb = xr[1], inc = xr[8];
  float u0 = inter2d_d(ts, te, tb, xr[2], amb) - inc;
  float u1 = inter2d_d(ts, te, tb, xr[3], amb) - inc;
  float u2 = amb, u3 = xr[9] - xr[10];
  float v[14] = {u0, u1, u2, u3,
                 u0 * u0, u0 * u1, u0 * u2, u0 * u3,
                 u1 * u1, u1 * u2, u1 * u3,
                 u2 * u2, u2 * u3, u3 * u3};
#pragma unroll
  for (int i = 0; i < 14; ++i) {
    float s = v[i];
    s += __shfl_xor(s, 32); s += __shfl_xor(s, 16); s += __shfl_xor(s, 8);
    s += __shfl_xor(s, 4);  s += __shfl_xor(s, 2);  s += __shfl_xor(s, 1);
    v[i] = s;
  }
  if ((t & 63) == 0)
    for (int i = 0; i < 14; ++i) atomicAdd(&bacc[i], v[i]);
  __syncthreads();
  if (t < 14) atomicAdd(&mom[t], bacc[t]);
}

// ---------- kernel 2: fold BN1 into A1[4][512], c1[512] ----------
__global__ void prep1_kernel(const float* __restrict__ mom,
                             const float* __restrict__ w1,
                             const float* __restrict__ g1,
                             const float* __restrict__ be1,
                             float* __restrict__ A1, float* __restrict__ c1,
                             float invB) {
  int j = threadIdx.x;  // 512
  float m0 = mom[0] * invB, m1 = mom[1] * invB, m2 = mom[2] * invB, m3 = mom[3] * invB;
  float C00 = mom[4]  * invB - m0 * m0, C01 = mom[5]  * invB - m0 * m1;
  float C02 = mom[6]  * invB - m0 * m2, C03 = mom[7]  * invB - m0 * m3;
  float C11 = mom[8]  * invB - m1 * m1, C12 = mom[9]  * invB - m1 * m2;
  float C13 = mom[10] * invB - m1 * m3, C22 = mom[11] * invB - m2 * m2;
  float C23 = mom[12] * invB - m2 * m3, C33 = mom[13] * invB - m3 * m3;
  float a = w1[j], b = w1[512 + j], c = w1[1024 + j], d = w1[1536 + j];
  float var = a * a * C00 + b * b * C11 + c * c * C22 + d * d * C33 +
              2.f * (a * b * C01 + a * c * C02 + a * d * C03 +
                     b * c * C12 + b * d * C13 + c * d * C23);
  float s1 = g1[j] * rsqrtf(fmaxf(var, 0.f) + 1e-5f);
  A1[j] = a * s1; A1[512 + j] = b * s1; A1[1024 + j] = c * s1; A1[1536 + j] = d * s1;
  c1[j] = be1[j] - (m0 * a + m1 * b + m2 * c + m3 * d) * s1;  // b1 cancels in BN
}

// ---------- kernel 3: w2 -> bf16, pre-swizzled per-iteration LDS image ----------
// layout: iter it (K-block of 32) | chunk c (0..3, 8 k's) | n (0..511) | 8 bf16
// global offset of 16B chunk = ((it*4+c)*512 + n)*16 ; content = w2[it*32+c*8+e][n]
__global__ void transpose_w2(const float* __restrict__ w2,
                             unsigned char* __restrict__ w2ts) {
  int q = blockIdx.x * 256 + threadIdx.x;  // 0..32767
  int n = q & 511;
  int kb = (q >> 9) * 8;  // q>>9 = it*4+c
  u32 pk[4];
#pragma unroll
  for (int e = 0; e < 8; e += 2) {
    u16 a = f2bf(w2[(size_t)(kb + e) * 512 + n]);
    u16 b = f2bf(w2[(size_t)(kb + e + 1) * 512 + n]);
    pk[e >> 1] = (u32)a | ((u32)b << 16);
  }
  *(uint4*)(w2ts + (size_t)q * 16) = make_uint4(pk[0], pk[1], pk[2], pk[3]);
}

// ---------- kernel 5: fold BN2 into s2,c2 (b2 cancels exactly) ----------
__global__ void prep2_kernel(const float* __restrict__ stat2,
                             const float* __restrict__ g2,
                             const float* __restrict__ be2,
                             float* __restrict__ s2, float* __restrict__ c2,
                             float invB) {
  int j = threadIdx.x;
  float mu = stat2[j] * invB;
  float ex2 = stat2[512 + j] * invB;
  float var = fmaxf(ex2 - mu * mu, 0.f);
  float s = g2[j] * rsqrtf(var + 1e-5f);
  s2[j] = s; c2[j] = be2[j] - mu * s;
}

// ---------- kernels 4 & 6: fused t1 + GEMM(t1 @ w2), two epilogues ----------
// EPI=0: per-column sum/sumsq of h2 -> stat2 (atomics)
// EPI=1: out[row] = sum_j tanh(h2*s2+c2)*w3 + b3
template <int EPI>
__global__ __launch_bounds__(512, 2) void gemm_fused(
    const float* __restrict__ x, const float* __restrict__ tsg,
    const float* __restrict__ teg, const float* __restrict__ tbg,
    const float* __restrict__ A1g, const float* __restrict__ c1g,
    const unsigned char* __restrict__ w2ts, float* __restrict__ stat2,
    const float* __restrict__ s2g, const float* __restrict__ c2g,
    const float* __restrict__ w3g, const float* __restrict__ b3g,
    float* __restrict__ out) {
  // t1: chunk-major, 16B chunk (m, c=k/8) at (c*64+m)*16  -> conflict-free b128 frags
  __shared__ __align__(16) unsigned char sm_t1[65536];
  __shared__ __align__(16) unsigned char sm_B[2][32768];  // (c*512+n)*16, c=0..3
  __shared__ float sm_A1[2048];
  __shared__ float sm_c1[512];
  __shared__ __align__(16) float sm_u[64][4];
  __shared__ float sm_ts[9], sm_te[14], sm_tb[126];

  const int t = threadIdx.x;
  const int l = t & 63, w = t >> 6;
  const int wm = w & 1, wn = w >> 1;       // wave tile: rows wm*32.., cols wn*128..
  const int hi = l >> 5, ln = l & 31;
  const int r0 = blockIdx.x * 64;

  // stage B buffer 0 (iter 0): 32 x 1KB contiguous global_load_lds
  {
    const unsigned char* g = w2ts;
#pragma unroll
    for (int q = 0; q < 4; ++q)
      glds16(g + (w * 4 + q) * 1024 + l * 16, sm_B[0] + (w * 4 + q) * 1024);
  }
  if (t < 9) sm_ts[t] = tsg[t];
  if (t < 14) sm_te[t] = teg[t];
  if (t < 126) sm_tb[t] = tbg[t];
#pragma unroll
  for (int q = 0; q < 4; ++q) sm_A1[q * 512 + t] = A1g[q * 512 + t];
  sm_c1[t] = c1g[t];
  __syncthreads();

  if (t < 64) {
    const float* xr = x + (size_t)(r0 + t) * 15;
    float amb = xr[1], inc = xr[8];
    sm_u[t][0] = inter2d_d(sm_ts, sm_te, sm_tb, xr[2], amb) - inc;
    sm_u[t][1] = inter2d_d(sm_ts, sm_te, sm_tb, xr[3], amb) - inc;
    sm_u[t][2] = amb;
    sm_u[t][3] = xr[9] - xr[10];
  }
  __syncthreads();

  // prologue: t1 = tanh(u@A1 + c1) in bf16, straight into frag layout.
  // lane l owns row l; wave w owns chunks w*8..w*8+7 (j = chunk*8..+7, wave-uniform)
  {
    float u0 = sm_u[l][0], u1 = sm_u[l][1], u2 = sm_u[l][2], u3 = sm_u[l][3];
#pragma unroll
    for (int ic = 0; ic < 8; ++ic) {
      int c = w * 8 + ic;
      u32 pk[4];
#pragma unroll
      for (int jj = 0; jj < 8; jj += 2) {
        int j0 = c * 8 + jj;
        float h0 = sm_c1[j0] + u0 * sm_A1[j0] + u1 * sm_A1[512 + j0] +
                   u2 * sm_A1[1024 + j0] + u3 * sm_A1[1536 + j0];
        float h1 = sm_c1[j0 + 1] + u0 * sm_A1[j0 + 1] + u1 * sm_A1[512 + j0 + 1] +
                   u2 * sm_A1[1024 + j0 + 1] + u3 * sm_A1[1536 + j0 + 1];
        h0 = fast_tanh(h0); h1 = fast_tanh(h1);
        pk[jj >> 1] = (u32)f2bf(h0) | ((u32)f2bf(h1) << 16);
      }
      *(uint4*)(sm_t1 + (c * 64 + l) * 16) = make_uint4(pk[0], pk[1], pk[2], pk[3]);
    }
  }
  __syncthreads();

  const u32 aoff = hi * 1024 + (wm * 32 + ln) * 16;
  const u32 boff = hi * 8192 + (wn * 128 + ln) * 16;
  f32x16 acc[4];
#pragma unroll
  for (int tt = 0; tt < 4; ++tt)
#pragma unroll
    for (int k = 0; k < 16; ++k) acc[tt][k] = 0.0f;

  // K loop: BK=32, 16 iters, double-buffered B staging
  for (int i = 0; i < 16; ++i) {
    if (i < 15) {
      const unsigned char* g = w2ts + (size_t)(i + 1) * 32768;
      unsigned char* d = sm_B[(i + 1) & 1];
#pragma unroll
      for (int q = 0; q < 4; ++q)
        glds16(g + (w * 4 + q) * 1024 + l * 16, d + (w * 4 + q) * 1024);
    }
    const unsigned char* bb = sm_B[i & 1];
#pragma unroll
    for (int s = 0; s < 2; ++s) {
      bf16x8 af = *(const bf16x8*)(sm_t1 + (i * 4 + s * 2) * 1024 + aoff);
#pragma unroll
      for (int tt = 0; tt < 4; ++tt) {
        bf16x8 bfr = *(const bf16x8*)(bb + s * 16384 + tt * 512 + boff);
        acc[tt] = __builtin_amdgcn_mfma_f32_32x32x16_bf16(af, bfr, acc[tt], 0, 0, 0);
      }
    }
    __syncthreads();
  }

  // C/D layout (32x32x16): col = lane&31, row = (reg&3) + 8*(reg>>2) + 4*hi
  if (EPI == 0) {
    float* red = (float*)sm_B[0];  // [8 waves][4 tiles][32 cols][2]
#pragma unroll
    for (int tt = 0; tt < 4; ++tt) {
      float s = 0.f, q = 0.f;
#pragma unroll
      for (int k = 0; k < 16; ++k) { float v = acc[tt][k]; s += v; q += v * v; }
      s += __shfl_xor(s, 32); q += __shfl_xor(q, 32);
      if (hi == 0) {
        red[((w * 4 + tt) * 32 + ln) * 2 + 0] = s;
        red[((w * 4 + tt) * 32 + ln) * 2 + 1] = q;
      }
    }
    __syncthreads();
    {
      int wnp = t >> 7, tile = (t >> 5) & 3, cc = t & 31;  // col == t
      int i0 = (((2 * wnp) * 4 + tile) * 32 + cc) * 2;
      int i1 = (((2 * wnp + 1) * 4 + tile) * 32 + cc) * 2;
      atomicAdd(&stat2[t], red[i0] + red[i1]);
      atomicAdd(&stat2[512 + t], red[i0 + 1] + red[i1 + 1]);
    }
  } else {
    float* pr = (float*)sm_B[0];  // [64 rows][4 wn]
    float sv[4], cv[4], wv[4];
#pragma unroll
    for (int tt = 0; tt < 4; ++tt) {
      int col = wn * 128 + tt * 32 + ln;
      sv[tt] = s2g[col]; cv[tt] = c2g[col]; wv[tt] = w3g[col];
    }
    float rs[16];
#pragma unroll
    for (int k = 0; k < 16; ++k) rs[k] = 0.f;
#pragma unroll
    for (int tt = 0; tt < 4; ++tt)
#pragma unroll
      for (int k = 0; k < 16; ++k)
        rs[k] += fast_tanh(acc[tt][k] * sv[tt] + cv[tt]) * wv[tt];
#pragma unroll
    for (int k = 0; k < 16; ++k) {
      float v = rs[k];
      v += __shfl_xor(v, 1); v += __shfl_xor(v, 2); v += __shfl_xor(v, 4);
      v += __shfl_xor(v, 8); v += __shfl_xor(v, 16);
      rs[k] = v;
    }
    if (ln == 0) {
#pragma unroll
      for (int k = 0; k < 16; ++k) {
        int row = (k & 3) + 8 * (k >> 2) + 4 * hi + wm * 32;
        pr[row * 4 + wn] = rs[k];
      }
    }
    __syncthreads();
    if (t < 64)
      out[r0 + t] = pr[t * 4] + pr[t * 4 + 1] + pr[t * 4 + 2] + pr[t * 4 + 3] + b3g[0];
  }
}

// ---------- launcher ----------
extern "C" void kernel_launch(void* const* d_in, const int* in_sizes, int n_in,
                              void* d_out, int out_size, void* d_ws, size_t ws_size,
                              hipStream_t stream) {
  const float* x   = (const float*)d_in[0];
  const float* ts  = (const float*)d_in[1];
  const float* te  = (const float*)d_in[2];
  const float* tab = (const float*)d_in[3];
  const float* w1  = (const float*)d_in[4];
  const float* g1  = (const float*)d_in[6];
  const float* be1 = (const float*)d_in[7];
  const float* w2  = (const float*)d_in[8];
  const float* g2  = (const float*)d_in[10];
  const float* be2 = (const float*)d_in[11];
  const float* w3  = (const float*)d_in[12];
  const float* b3  = (const float*)d_in[13];
  float* out = (float*)d_out;
  char* ws = (char*)d_ws;

  if (ws_size < (size_t)(32768 + 524288)) return;  // need ~560 KB scratch

  int Bn = in_sizes[0] / 15;  // 262144
  float invB = 1.0f / (float)Bn;

  float* mom   = (float*)(ws + 0);      // 14 f32 (zeroed)
  float* stat2 = (float*)(ws + 64);     // 1024 f32 (zeroed)
  float* A1    = (float*)(ws + 4160);   // 2048 f32
  float* c1    = (float*)(ws + 12352);  // 512 f32
  float* s2    = (float*)(ws + 14400);  // 512 f32
  float* c2    = (float*)(ws + 16448);  // 512 f32
  unsigned char* w2ts = (unsigned char*)(ws + 32768);  // 512 KB bf16 image

  hipMemsetAsync(ws, 0, 4160, stream);
  stats1_kernel<<<Bn / 256, 256, 0, stream>>>(x, ts, te, tab, mom);
  prep1_kernel<<<1, 512, 0, stream>>>(mom, w1, g1, be1, A1, c1, invB);
  transpose_w2<<<128, 256, 0, stream>>>(w2, w2ts);
  gemm_fused<0><<<Bn / 64, 512, 0, stream>>>(x, ts, te, tab, A1, c1, w2ts, stat2,
                                             nullptr, nullptr, nullptr, nullptr, nullptr);
  prep2_kernel<<<1, 512, 0, stream>>>(stat2, g2, be2, s2, c2, invB);
  gemm_fused<1><<<Bn / 64, 512, 0, stream>>>(x, ts, te, tab, A1, c1, w2ts, stat2,
                                             s2, c2, w3, b3, out);
}

// Round 2
// 524.437 us; speedup vs baseline: 1.3015x; 1.3015x over previous
//
#include <hip/hip_runtime.h>

typedef unsigned int u32;
typedef unsigned short u16;
typedef __bf16 bf16x8 __attribute__((ext_vector_type(8)));
typedef float f32x16 __attribute__((ext_vector_type(16)));

// ---------- helpers ----------
__device__ __forceinline__ u16 f2bf(float f) {
  u32 u = __float_as_uint(f);
  u32 r = (u + 0x7FFFu + ((u >> 16) & 1u)) >> 16;
  return (u16)r;
}

__device__ __forceinline__ float fast_tanh(float x) {
  float e = __expf(2.0f * x);
  return 1.0f - 2.0f * __builtin_amdgcn_rcpf(e + 1.0f);
}

// bilinear interp matching jnp.searchsorted(side='right')-1 with clamping
__device__ __forceinline__ float inter2d_d(const float* xs, const float* ys,
                                           const float* tb, float xq, float yq) {
  xq = fminf(fmaxf(xq, xs[0]), xs[8]);
  yq = fminf(fmaxf(yq, ys[0]), ys[13]);
  int i = 0, j = 0;
#pragma unroll
  for (int k = 1; k <= 8; ++k) if (xq >= xs[k]) i = k;
#pragma unroll
  for (int k = 1; k <= 13; ++k) if (yq >= ys[k]) j = k;
  if (i > 7) i = 7;
  if (j > 12) j = 12;
  float x0 = xs[i], x1 = xs[i + 1], y0 = ys[j], y1 = ys[j + 1];
  float tx = (xq - x0) / (x1 - x0);
  float ty = (yq - y0) / (y1 - y0);
  float f00 = tb[i * 14 + j], f01 = tb[i * 14 + j + 1];
  float f10 = tb[(i + 1) * 14 + j], f11 = tb[(i + 1) * 14 + j + 1];
  return f00 * (1 - tx) * (1 - ty) + f10 * tx * (1 - ty) +
         f01 * (1 - tx) * ty + f11 * tx * ty;
}

// ---------- kernel 1: moments of u (4 means + 10 second moments) ----------
__global__ void stats1_kernel(const float* __restrict__ x,
                              const float* __restrict__ tsg,
                              const float* __restrict__ teg,
                              const float* __restrict__ tbg,
                              float* __restrict__ mom) {
  __shared__ float ts[9], te[14], tb[126], bacc[14];
  int t = threadIdx.x;
  if (t < 9) ts[t] = tsg[t];
  if (t < 14) { te[t] = teg[t]; bacc[t] = 0.f; }
  if (t < 126) tb[t] = tbg[t];
  __syncthreads();
  const float* xr = x + (size_t)(blockIdx.x * 256 + t) * 15;
  float amb = xr[1], inc = xr[8];
  float u0 = inter2d_d(ts, te, tb, xr[2], amb) - inc;
  float u1 = inter2d_d(ts, te, tb, xr[3], amb) - inc;
  float u2 = amb, u3 = xr[9] - xr[10];
  float v[14] = {u0, u1, u2, u3,
                 u0 * u0, u0 * u1, u0 * u2, u0 * u3,
                 u1 * u1, u1 * u2, u1 * u3,
                 u2 * u2, u2 * u3, u3 * u3};
#pragma unroll
  for (int i = 0; i < 14; ++i) {
    float s = v[i];
    s += __shfl_xor(s, 32); s += __shfl_xor(s, 16); s += __shfl_xor(s, 8);
    s += __shfl_xor(s, 4);  s += __shfl_xor(s, 2);  s += __shfl_xor(s, 1);
    v[i] = s;
  }
  if ((t & 63) == 0)
    for (int i = 0; i < 14; ++i) atomicAdd(&bacc[i], v[i]);
  __syncthreads();
  if (t < 14) atomicAdd(&mom[t], bacc[t]);
}

// ---------- kernel 2: fold BN1 into A1[4][512], c1[512] ----------
__global__ void prep1_kernel(const float* __restrict__ mom,
                             const float* __restrict__ w1,
                             const float* __restrict__ g1,
                             const float* __restrict__ be1,
                             float* __restrict__ A1, float* __restrict__ c1,
                             float invB) {
  int j = threadIdx.x;  // 512
  float m0 = mom[0] * invB, m1 = mom[1] * invB, m2 = mom[2] * invB, m3 = mom[3] * invB;
  float C00 = mom[4]  * invB - m0 * m0, C01 = mom[5]  * invB - m0 * m1;
  float C02 = mom[6]  * invB - m0 * m2, C03 = mom[7]  * invB - m0 * m3;
  float C11 = mom[8]  * invB - m1 * m1, C12 = mom[9]  * invB - m1 * m2;
  float C13 = mom[10] * invB - m1 * m3, C22 = mom[11] * invB - m2 * m2;
  float C23 = mom[12] * invB - m2 * m3, C33 = mom[13] * invB - m3 * m3;
  float a = w1[j], b = w1[512 + j], c = w1[1024 + j], d = w1[1536 + j];
  float var = a * a * C00 + b * b * C11 + c * c * C22 + d * d * C33 +
              2.f * (a * b * C01 + a * c * C02 + a * d * C03 +
                     b * c * C12 + b * d * C13 + c * d * C23);
  float s1 = g1[j] * rsqrtf(fmaxf(var, 0.f) + 1e-5f);
  A1[j] = a * s1; A1[512 + j] = b * s1; A1[1024 + j] = c * s1; A1[1536 + j] = d * s1;
  c1[j] = be1[j] - (m0 * a + m1 * b + m2 * c + m3 * d) * s1;  // b1 cancels in BN
}

// ---------- kernel 3: w2 -> bf16, frag-contiguous image ----------
// chunk index q = (it*4 + c)*512 + n ; content = w2[it*32 + c*8 + e][n], e=0..7
__global__ void transpose_w2(const float* __restrict__ w2,
                             unsigned char* __restrict__ w2ts) {
  int q = blockIdx.x * 256 + threadIdx.x;  // 0..32767
  int n = q & 511;
  int kb = (q >> 9) * 8;
  u32 pk[4];
#pragma unroll
  for (int e = 0; e < 8; e += 2) {
    u16 a = f2bf(w2[(size_t)(kb + e) * 512 + n]);
    u16 b = f2bf(w2[(size_t)(kb + e + 1) * 512 + n]);
    pk[e >> 1] = (u32)a | ((u32)b << 16);
  }
  *(uint4*)(w2ts + (size_t)q * 16) = make_uint4(pk[0], pk[1], pk[2], pk[3]);
}

// ---------- kernel 5: fold BN2 into s2,c2 (b2 cancels exactly) ----------
__global__ void prep2_kernel(const float* __restrict__ stat2,
                             const float* __restrict__ g2,
                             const float* __restrict__ be2,
                             float* __restrict__ s2, float* __restrict__ c2,
                             float invB) {
  int j = threadIdx.x;
  float mu = stat2[j] * invB;
  float ex2 = stat2[512 + j] * invB;
  float var = fmaxf(ex2 - mu * mu, 0.f);
  float s = g2[j] * rsqrtf(var + 1e-5f);
  s2[j] = s; c2[j] = be2[j] - mu * s;
}

// ---------- kernels 4 & 6: fused t1 + GEMM(t1 @ w2) ----------
// Block: 256 threads = 4 waves; M=64 rows, N=512 cols; wave tile 64x128.
// A (t1) in LDS, frag-chunk-major. B fragments loaded DIRECTLY from L2-resident
// w2ts image into VGPRs (no LDS staging, no K-loop barriers), reg-double-buffered.
template <int EPI>
__global__ __launch_bounds__(256, 2) void gemm_fused(
    const float* __restrict__ x, const float* __restrict__ tsg,
    const float* __restrict__ teg, const float* __restrict__ tbg,
    const float* __restrict__ A1g, const float* __restrict__ c1g,
    const unsigned char* __restrict__ w2ts, float* __restrict__ stat2,
    const float* __restrict__ s2g, const float* __restrict__ c2g,
    const float* __restrict__ w3g, const float* __restrict__ b3g,
    float* __restrict__ out) {
  __shared__ __align__(16) unsigned char sm_t1[65536];  // chunk (c*64+row)*16
  __shared__ float sm_A1[2048];
  __shared__ float sm_c1[512];
  __shared__ __align__(16) float sm_u[64][4];           // reused as pr[64][4] in EPI=1
  __shared__ float sm_ts[9], sm_te[14], sm_tb[126];

  const int t = threadIdx.x;
  const int w = t >> 6, l = t & 63;   // wave w: cols w*128..+127
  const int hi = l >> 5, ln = l & 31;
  const int r0 = blockIdx.x * 64;

  // B frag pointer (uint4 units). frag(it,s,nt) = bp[it*2048 + s*1024 + nt*32]
  const uint4* bp = (const uint4*)w2ts + (size_t)hi * 512 + w * 128 + ln;

  uint4 b0[8], b1[8];
  auto loadB = [&](uint4* dst, const uint4* src) {
#pragma unroll
    for (int s = 0; s < 2; ++s)
#pragma unroll
      for (int nt = 0; nt < 4; ++nt) dst[s * 4 + nt] = src[s * 1024 + nt * 32];
  };
  loadB(b0, bp);  // issue iter-0 loads now; they complete during the prologue

  // stage constants
  if (t < 9) sm_ts[t] = tsg[t];
  if (t < 14) sm_te[t] = teg[t];
  if (t < 126) sm_tb[t] = tbg[t];
#pragma unroll
  for (int q = 0; q < 8; ++q) sm_A1[q * 256 + t] = A1g[q * 256 + t];
  sm_c1[t] = c1g[t];
  sm_c1[256 + t] = c1g[256 + t];
  __syncthreads();

  if (t < 64) {
    const float* xr = x + (size_t)(r0 + t) * 15;
    float amb = xr[1], inc = xr[8];
    sm_u[t][0] = inter2d_d(sm_ts, sm_te, sm_tb, xr[2], amb) - inc;
    sm_u[t][1] = inter2d_d(sm_ts, sm_te, sm_tb, xr[3], amb) - inc;
    sm_u[t][2] = amb;
    sm_u[t][3] = xr[9] - xr[10];
  }
  __syncthreads();

  // prologue: t1 = tanh(u@A1 + c1) bf16 into frag layout.
  // thread t: row = l... (t&63), chunks c = w*16..w*16+15 (wave-uniform -> LDS broadcast)
  {
    float u0 = sm_u[t & 63][0], u1 = sm_u[t & 63][1];
    float u2 = sm_u[t & 63][2], u3 = sm_u[t & 63][3];
#pragma unroll
    for (int ic = 0; ic < 16; ++ic) {
      int c = w * 16 + ic;
      u32 pk[4];
#pragma unroll
      for (int jj = 0; jj < 8; jj += 2) {
        int j0 = c * 8 + jj;
        float h0 = sm_c1[j0] + u0 * sm_A1[j0] + u1 * sm_A1[512 + j0] +
                   u2 * sm_A1[1024 + j0] + u3 * sm_A1[1536 + j0];
        float h1 = sm_c1[j0 + 1] + u0 * sm_A1[j0 + 1] + u1 * sm_A1[512 + j0 + 1] +
                   u2 * sm_A1[1024 + j0 + 1] + u3 * sm_A1[1536 + j0 + 1];
        h0 = fast_tanh(h0); h1 = fast_tanh(h1);
        pk[jj >> 1] = (u32)f2bf(h0) | ((u32)f2bf(h1) << 16);
      }
      *(uint4*)(sm_t1 + ((size_t)c * 64 + (t & 63)) * 16) = make_uint4(pk[0], pk[1], pk[2], pk[3]);
    }
  }
  __syncthreads();

  f32x16 acc[8];  // [mt*4+nt]
#pragma unroll
  for (int i = 0; i < 8; ++i)
#pragma unroll
    for (int k = 0; k < 16; ++k) acc[i][k] = 0.0f;

  auto step = [&](int it, const uint4* bbuf) {
#pragma unroll
    for (int s = 0; s < 2; ++s) {
      int cb = (it * 4 + 2 * s + hi) * 64;
      bf16x8 a0 = *(const bf16x8*)(sm_t1 + (size_t)(cb + ln) * 16);
      bf16x8 a1 = *(const bf16x8*)(sm_t1 + (size_t)(cb + 32 + ln) * 16);
#pragma unroll
      for (int nt = 0; nt < 4; ++nt) {
        bf16x8 bv = __builtin_bit_cast(bf16x8, bbuf[s * 4 + nt]);
        acc[nt]     = __builtin_amdgcn_mfma_f32_32x32x16_bf16(a0, bv, acc[nt], 0, 0, 0);
        acc[4 + nt] = __builtin_amdgcn_mfma_f32_32x32x16_bf16(a1, bv, acc[4 + nt], 0, 0, 0);
      }
    }
  };

  // K loop: 16 iters of BK=32, manually 2x unrolled, NO barriers.
#pragma unroll 1
  for (int it2 = 0; it2 < 8; ++it2) {
    int it = it2 * 2;
    loadB(b1, bp + (size_t)(it + 1) * 2048);
    step(it, b0);
    if (it2 < 7) loadB(b0, bp + (size_t)(it + 2) * 2048);
    step(it + 1, b1);
  }

  // C/D layout (32x32x16): col = lane&31, row_in_tile = (k&3) + 8*(k>>2) + 4*hi
  if (EPI == 0) {
#pragma unroll
    for (int nt = 0; nt < 4; ++nt) {
      float s = 0.f, q = 0.f;
#pragma unroll
      for (int mt = 0; mt < 2; ++mt)
#pragma unroll
        for (int k = 0; k < 16; ++k) {
          float v = acc[mt * 4 + nt][k];
          s += v; q += v * v;
        }
      s += __shfl_xor(s, 32); q += __shfl_xor(q, 32);
      if (hi == 0) {
        int col = w * 128 + nt * 32 + ln;
        atomicAdd(&stat2[col], s);
        atomicAdd(&stat2[512 + col], q);
      }
    }
  } else {
    float sv[4], cv[4], wv[4];
#pragma unroll
    for (int nt = 0; nt < 4; ++nt) {
      int col = w * 128 + nt * 32 + ln;
      sv[nt] = s2g[col]; cv[nt] = c2g[col]; wv[nt] = w3g[col];
    }
    float rs[2][16];
#pragma unroll
    for (int mt = 0; mt < 2; ++mt)
#pragma unroll
      for (int k = 0; k < 16; ++k) rs[mt][k] = 0.f;
#pragma unroll
    for (int nt = 0; nt < 4; ++nt)
#pragma unroll
      for (int mt = 0; mt < 2; ++mt)
#pragma unroll
        for (int k = 0; k < 16; ++k)
          rs[mt][k] += fast_tanh(acc[mt * 4 + nt][k] * sv[nt] + cv[nt]) * wv[nt];
    float* pr = &sm_u[0][0];  // reuse as [64 rows][4 waves]
#pragma unroll
    for (int mt = 0; mt < 2; ++mt)
#pragma unroll
      for (int k = 0; k < 16; ++k) {
        float v = rs[mt][k];
        v += __shfl_xor(v, 1); v += __shfl_xor(v, 2); v += __shfl_xor(v, 4);
        v += __shfl_xor(v, 8); v += __shfl_xor(v, 16);
        if (ln == 0) {
          int row = mt * 32 + (k & 3) + 8 * (k >> 2) + 4 * hi;
          pr[row * 4 + w] = v;
        }
      }
    __syncthreads();
    if (t < 64)
      out[r0 + t] = pr[t * 4] + pr[t * 4 + 1] + pr[t * 4 + 2] + pr[t * 4 + 3] + b3g[0];
  }
}

// ---------- launcher ----------
extern "C" void kernel_launch(void* const* d_in, const int* in_sizes, int n_in,
                              void* d_out, int out_size, void* d_ws, size_t ws_size,
                              hipStream_t stream) {
  const float* x   = (const float*)d_in[0];
  const float* ts  = (const float*)d_in[1];
  const float* te  = (const float*)d_in[2];
  const float* tab = (const float*)d_in[3];
  const float* w1  = (const float*)d_in[4];
  const float* g1  = (const float*)d_in[6];
  const float* be1 = (const float*)d_in[7];
  const float* w2  = (const float*)d_in[8];
  const float* g2  = (const float*)d_in[10];
  const float* be2 = (const float*)d_in[11];
  const float* w3  = (const float*)d_in[12];
  const float* b3  = (const float*)d_in[13];
  float* out = (float*)d_out;
  char* ws = (char*)d_ws;

  if (ws_size < (size_t)(32768 + 524288)) return;

  int Bn = in_sizes[0] / 15;  // 262144
  float invB = 1.0f / (float)Bn;

  float* mom   = (float*)(ws + 0);      // 14 f32 (zeroed)
  float* stat2 = (float*)(ws + 64);     // 1024 f32 (zeroed)
  float* A1    = (float*)(ws + 4160);   // 2048 f32
  float* c1    = (float*)(ws + 12352);  // 512 f32
  float* s2    = (float*)(ws + 14400);  // 512 f32
  float* c2    = (float*)(ws + 16448);  // 512 f32
  unsigned char* w2ts = (unsigned char*)(ws + 32768);  // 512 KB bf16 image

  hipMemsetAsync(ws, 0, 4160, stream);
  stats1_kernel<<<Bn / 256, 256, 0, stream>>>(x, ts, te, tab, mom);
  prep1_kernel<<<1, 512, 0, stream>>>(mom, w1, g1, be1, A1, c1, invB);
  transpose_w2<<<128, 256, 0, stream>>>(w2, w2ts);
  gemm_fused<0><<<Bn / 64, 256, 0, stream>>>(x, ts, te, tab, A1, c1, w2ts, stat2,
                                             nullptr, nullptr, nullptr, nullptr, nullptr);
  prep2_kernel<<<1, 512, 0, stream>>>(stat2, g2, be2, s2, c2, invB);
  gemm_fused<1><<<Bn / 64, 256, 0, stream>>>(x, ts, te, tab, A1, c1, w2ts, stat2,
                                             s2, c2, w3, b3, out);
}